// Round 4
// baseline (2349.881 us; speedup 1.0000x reference)
//
#include <hip/hip_runtime.h>
#include <math.h>

#define NPRED  25200
#define BATCH  16
#define NC     80
#define MAXDET 300
#define NDIM   87

// ---------------------------------------------------------------------------
// Prep: LDS-staged coalesced loads (rows are 340 B; direct per-thread row
// reads over-fetch 4x). All arithmetic unfused-rn to match numpy fp32
// bit-exactly (selection decisions depend on exact values).
// ---------------------------------------------------------------------------
#define PREP_TPB 256
#define PB 128

__global__ __launch_bounds__(PREP_TPB)
void prep_kernel(const float* __restrict__ pred,
                 float* __restrict__ sc,
                 float4* __restrict__ box) {
    __shared__ float4 s4[PB * 85 / 4];
    float* s = (float*)s4;
    const int t = threadIdx.x;
    const float4* p4 = (const float4*)(pred + (size_t)blockIdx.x * (PB * 85));
    for (int i = t; i < PB * 85 / 4; i += PREP_TPB) s4[i] = p4[i];
    __syncthreads();
    if (t < PB) {
        const float* row = s + t * 85;
        float x = row[0], y = row[1], w = row[2], h = row[3], obj = row[4];
        float best = -INFINITY;
        #pragma unroll 8
        for (int c = 0; c < NC; ++c) {
            float v = __fmul_rn(row[5 + c], obj);
            if (v > best) best = v;          // strict >: first index on ties
        }
        float hw = __fmul_rn(w, 0.5f), hh = __fmul_rn(h, 0.5f);
        bool valid = (obj > 0.25f) && (best > 0.25f);
        int g = blockIdx.x * PB + t;
        sc[g]  = valid ? best : -INFINITY;
        box[g] = make_float4(__fsub_rn(x, hw), __fsub_rn(y, hh),
                             __fadd_rn(x, hw), __fadd_rn(y, hh));
    }
}

// ---------------------------------------------------------------------------
// NMS: one block per image. Round-4 structure: ONLY scores live in registers
// (25/thread @ 1024 threads -> ~90 VGPR total demand, safely under the
// 128-VGPR cap: no spill, unlike rounds 2-3 where box arrays spilled).
// Boxes are re-streamed from L2 every iteration with UNCONDITIONAL coalesced
// float4 loads (400 KB/image, L2-resident; hidden under VALU by 4 waves/SIMD
// of MLP). Suppression work is pure VALU throughput on top of that stream.
// Single barrier per iteration (parity-double-buffered leader slots; every
// thread redundantly reduces the 16 wave leaders -> uniform result, uniform
// break, no second barrier).
// IoU test: fdiv_rn(inter,denom) > 0.45f  <=>  inter > K*denom exactly,
// K = (double)0.45f + 2^-26 (0.45f mantissa even => midpoint rounds down;
// 25-bit x 24-bit f64 product is exact), so selection is bit-identical.
// ---------------------------------------------------------------------------
#define TPB   1024
#define EPT   25                 // 1024*25 = 25600 >= 25200
#define NWAVE (TPB / 64)

__global__ __launch_bounds__(TPB)
void nms_kernel(const float* __restrict__ sc_g,
                const float4* __restrict__ box_g,
                int* __restrict__ selidx,
                int* __restrict__ selcnt) {
    __shared__ float s_v[2][NWAVE];
    __shared__ int   s_i[2][NWAVE];
    const int img = blockIdx.x, t = threadIdx.x;
    const float*  sci = sc_g  + (size_t)img * NPRED;
    const float4* bxi = box_g + (size_t)img * NPRED;

    float sc[EPT];
    #pragma unroll
    for (int i = 0; i < EPT; ++i) {
        int e = t + i * TPB;
        sc[i] = (e < NPRED) ? sci[e] : -INFINITY;
    }

    const double K = (double)0.45f + 0x1p-26;

    int n = 0;
    for (int it = 0; it < MAXDET; ++it) {
        // ---- local argmax (ascending e; strict > keeps first index) ----
        float bv = -INFINITY; int bi = 0x7FFFFFFF;
        #pragma unroll
        for (int i = 0; i < EPT; ++i)
            if (sc[i] > bv) { bv = sc[i]; bi = t + i * TPB; }
        // ---- wave reduce ----
        #pragma unroll
        for (int off = 32; off > 0; off >>= 1) {
            float ov = __shfl_down(bv, off);
            int   oi = __shfl_down(bi, off);
            if (ov > bv || (ov == bv && oi < bi)) { bv = ov; bi = oi; }
        }
        const int par = it & 1;
        if ((t & 63) == 0) { s_v[par][t >> 6] = bv; s_i[par][t >> 6] = bi; }
        __syncthreads();
        // ---- every thread reduces the 16 leader pairs (broadcast reads);
        //      result is uniform -> no second barrier, uniform break ----
        bv = s_v[par][0]; bi = s_i[par][0];
        #pragma unroll
        for (int w = 1; w < NWAVE; ++w) {
            float ov = s_v[par][w]; int oi = s_i[par][w];
            if (ov > bv || (ov == bv && oi < bi)) { bv = ov; bi = oi; }
        }
        if (bv == -INFINITY) break;
        if (t == 0) selidx[img * MAXDET + it] = bi;
        n = it + 1;

        float4 B = bxi[bi];   // lane-uniform broadcast load (L2)
        float barea = __fmul_rn(__fsub_rn(B.z, B.x), __fsub_rn(B.w, B.y));

        // ---- suppression: unconditional L2 stream + VALU. Slice 24's
        //      tail lanes clamp the address (their sc is already -inf, so
        //      the redundant test is harmless). Selected box suppresses
        //      itself via IoU~1, matching the reference's where(). ----
        #pragma unroll
        for (int i = 0; i < EPT; ++i) {
            int e = t + i * TPB;
            if (i == EPT - 1 && e >= NPRED) e = NPRED - 1;   // compile-time split
            float4 b = bxi[e];
            float lx = fmaxf(B.x, b.x), ly = fmaxf(B.y, b.y);
            float rx = fminf(B.z, b.z), ry = fminf(B.w, b.w);
            float ww  = fmaxf(__fsub_rn(rx, lx), 0.0f);
            float hh2 = fmaxf(__fsub_rn(ry, ly), 0.0f);
            float inter = __fmul_rn(ww, hh2);
            float a = __fmul_rn(__fsub_rn(b.z, b.x), __fsub_rn(b.w, b.y));
            float denom = __fadd_rn(__fsub_rn(__fadd_rn(barea, a), inter), 1e-9f);
            if ((double)inter > K * (double)denom) sc[i] = -INFINITY;
        }
    }
    if (t == 0) selcnt[img] = n;
}

// ---------------------------------------------------------------------------
// Gather: writes every output element (zeros for padding rows — no memset
// needed). conf/cls/obj recomputed from pred with the identical rn ops.
// ---------------------------------------------------------------------------
#define GT 256

__global__ __launch_bounds__(GT)
void gather_kernel(const float* __restrict__ pred,
                   const float4* __restrict__ box,
                   const float* __restrict__ logits,
                   const int* __restrict__ selidx,
                   const int* __restrict__ selcnt,
                   float* __restrict__ out) {
    int tid = blockIdx.x * GT + threadIdx.x;
    if (tid >= BATCH * MAXDET * NDIM) return;
    int row = tid / NDIM, col = tid - row * NDIM;
    int img = row / MAXDET, det = row - img * MAXDET;
    float v = 0.0f;
    if (det < selcnt[img]) {
        int s = selidx[img * MAXDET + det];
        size_t g = (size_t)img * NPRED + s;
        if (col < 4) {
            float4 b = box[g];
            v = (col == 0) ? b.x : (col == 1) ? b.y : (col == 2) ? b.z : b.w;
        } else if (col == 6) {
            v = pred[g * 85 + 4];
        } else if (col >= 7) {
            v = logits[g * NC + (col - 7)];
        } else {
            const float* p = pred + g * 85;
            float obj = p[4];
            float best = -INFINITY; int bc = 0;
            #pragma unroll 8
            for (int c = 0; c < NC; ++c) {
                float q = __fmul_rn(p[5 + c], obj);
                if (q > best) { best = q; bc = c; }
            }
            v = (col == 4) ? best : (float)bc;
        }
    }
    out[tid] = v;
}

extern "C" void kernel_launch(void* const* d_in, const int* in_sizes, int n_in,
                              void* d_out, int out_size, void* d_ws, size_t ws_size,
                              hipStream_t stream) {
    const float* pred   = (const float*)d_in[0];
    const float* logits = (const float*)d_in[1];
    float* out = (float*)d_out;

    char* ws = (char*)d_ws;
    float*  sc     = (float*)ws;                                   // 1,612,800 B
    float4* box    = (float4*)(ws + 1612800);                      // 6,451,200 B
    int*    selidx = (int*)(ws + 1612800 + 6451200);               //    19,200 B
    int*    selcnt = (int*)(ws + 1612800 + 6451200 + 19200);       //        64 B

    prep_kernel<<<BATCH * NPRED / PB, PREP_TPB, 0, stream>>>(pred, sc, box);
    nms_kernel<<<BATCH, TPB, 0, stream>>>(sc, box, selidx, selcnt);
    int gtot = BATCH * MAXDET * NDIM;
    gather_kernel<<<(gtot + GT - 1) / GT, GT, 0, stream>>>(pred, box, logits, selidx, selcnt, out);
}

// Round 5
// 735.473 us; speedup vs baseline: 3.1951x; 3.1951x over previous
//
#include <hip/hip_runtime.h>
#include <math.h>

#define NPRED  25200
#define BATCH  16
#define NC     80
#define MAXDET 300
#define NDIM   87

// ---------------------------------------------------------------------------
// Prep: LDS-staged coalesced loads. All arithmetic unfused-rn to match numpy
// fp32 bit-exactly (selection decisions depend on exact values). Validated.
// ---------------------------------------------------------------------------
#define PREP_TPB 256
#define PB 128

__global__ __launch_bounds__(PREP_TPB)
void prep_kernel(const float* __restrict__ pred,
                 float* __restrict__ sc,
                 float4* __restrict__ box) {
    __shared__ float4 s4[PB * 85 / 4];
    float* s = (float*)s4;
    const int t = threadIdx.x;
    const float4* p4 = (const float4*)(pred + (size_t)blockIdx.x * (PB * 85));
    for (int i = t; i < PB * 85 / 4; i += PREP_TPB) s4[i] = p4[i];
    __syncthreads();
    if (t < PB) {
        const float* row = s + t * 85;
        float x = row[0], y = row[1], w = row[2], h = row[3], obj = row[4];
        float best = -INFINITY;
        #pragma unroll 8
        for (int c = 0; c < NC; ++c) {
            float v = __fmul_rn(row[5 + c], obj);
            if (v > best) best = v;          // strict >: first index on ties
        }
        float hw = __fmul_rn(w, 0.5f), hh = __fmul_rn(h, 0.5f);
        bool valid = (obj > 0.25f) && (best > 0.25f);
        int g = blockIdx.x * PB + t;
        sc[g]  = valid ? best : -INFINITY;
        box[g] = make_float4(__fsub_rn(x, hw), __fsub_rn(y, hh),
                             __fadd_rn(x, hw), __fadd_rn(y, hh));
    }
}

// ---------------------------------------------------------------------------
// NMS via sort-and-sweep (exactly equivalent to repeated argmax+suppress):
// process candidates in (score desc, index asc) order; keep iff no earlier-
// kept box has IoU > 0.45 with it. Tie order matches jnp.argmax (first index).
// Degenerate exactness: a kept box whose self-IoU <= 0.45 (area ~ 0) is never
// suppressed in the reference and is re-selected for every remaining slot ->
// "sticky" fill, using the reference's exact self-IoU arithmetic.
// Candidates are carved into <=8192-candidate tranches by a 1024-bin score
// histogram (valid scores lie in (0.25,1), monotone in the f32 bit pattern),
// sorted exactly by packed (~scorebits, index) u64 keys with an LDS bitonic
// sort, then swept: phase A kills candidates vs previously-kept boxes in
// parallel; phase B appends survivors in order (8 IoU/thread + 2 barriers
// per kept box). IoU decision uses the exact double-compare:
// fdiv_rn(i,d) > 0.45f  <=>  (double)i > K*(double)d, K = (double)0.45f+2^-26
// (0.45f mantissa even => midpoint rounds down; 26b x 24b f64 product exact).
// ---------------------------------------------------------------------------
#define TPB    1024
#define NBIN   1024
#define TCAP   8192
#define SLOTS  8                 // TCAP / TPB
#define NW     (TPB / 64)
#define EPTS   25                // ceil(NPRED / TPB)

__global__ __launch_bounds__(TPB)
void nms_kernel(const float* __restrict__ sc_g,
                const float4* __restrict__ box_g,
                int* __restrict__ selidx,
                int* __restrict__ selcnt) {
    __shared__ unsigned long long sbuf[TCAP];        // sort buffer / wave hists
    __shared__ unsigned int scanA[NBIN];
    __shared__ unsigned int scanB[NBIN];
    __shared__ float4 kbox[MAXDET];
    __shared__ int s_redA[2][NW];
    __shared__ int s_redB[NW];
    __shared__ int s_sticky, s_stickyIdx, s_cnt;

    const int img = blockIdx.x, t = threadIdx.x, wid = t >> 6;
    const float*  sci = sc_g  + (size_t)img * NPRED;
    const float4* bxi = box_g + (size_t)img * NPRED;
    const double K = (double)0.45f + 0x1p-26;

    // ---- histogram: 16 per-wave copies overlaid on sbuf (zero conflicts
    //      across waves), then reduce ----
    unsigned int (*whist)[NBIN] = (unsigned int (*)[NBIN])sbuf;
    for (int i = t; i < NW * NBIN; i += TPB) ((unsigned int*)sbuf)[i] = 0u;
    __syncthreads();
    #pragma unroll
    for (int i = 0; i < EPTS; ++i) {
        int e = t + i * TPB;
        if (e < NPRED) {
            float s = sci[e];
            if (s != -INFINITY) {
                unsigned int sb = __float_as_uint(s);
                atomicAdd(&whist[wid][(sb - 0x3E800000u) >> 14], 1u);
            }
        }
    }
    __syncthreads();
    unsigned int csum = 0;
    #pragma unroll
    for (int w = 0; w < NW; ++w) csum += whist[w][t];
    scanA[t] = csum;
    __syncthreads();
    // ---- inclusive suffix-sum I[b] = sum_{b'>=b} cnt[b'] (ping-pong) ----
    unsigned int* src = scanA; unsigned int* dst = scanB;
    for (int d = 1; d < NBIN; d <<= 1) {
        unsigned int v = src[t] + ((t + d) < NBIN ? src[t + d] : 0u);
        dst[t] = v;
        __syncthreads();
        unsigned int* tmp = src; src = dst; dst = tmp;
    }
    unsigned int* Ia = src;                  // 10 steps (even) -> scanA
    int n_valid = (int)Ia[0];

    int o = 0, b_hi = NBIN, kept = 0;
    while (kept < MAXDET && o < n_valid) {
        // ---- pick bin range [b_lo, b_hi): largest window <= TCAP ----
        int vb = (t < b_hi && ((int)Ia[t] - o) <= TCAP) ? t : 0x7FFFFFFF;
        #pragma unroll
        for (int off = 32; off; off >>= 1) vb = min(vb, __shfl_down(vb, off));
        if ((t & 63) == 0) s_redB[wid] = vb;
        __syncthreads();
        int b_lo = s_redB[0];
        #pragma unroll
        for (int w = 1; w < NW; ++w) b_lo = min(b_lo, s_redB[w]);
        int c;
        if (b_lo == 0x7FFFFFFF) {
            // pathological: a single bin exceeds TCAP (P~0 for real f32 data);
            // take the first nonempty bin, clamped (memory-safe, deterministic)
            __syncthreads();
            int vb2 = (t < b_hi && ((int)Ia[t] - o) > 0) ? -t : 0x7FFFFFFF;
            #pragma unroll
            for (int off = 32; off; off >>= 1) vb2 = min(vb2, __shfl_down(vb2, off));
            if ((t & 63) == 0) s_redB[wid] = vb2;
            __syncthreads();
            int m2 = s_redB[0];
            #pragma unroll
            for (int w = 1; w < NW; ++w) m2 = min(m2, s_redB[w]);
            b_lo = -m2;
            c = min((int)Ia[b_lo] - o, TCAP);
        } else {
            c = (int)Ia[b_lo] - o;
        }
        if (c <= 0) break;

        // ---- pad + scatter tranche candidates (order fixed by sort) ----
        for (int s2 = t; s2 < TCAP; s2 += TPB) sbuf[s2] = ~0ULL;
        if (t == 0) s_cnt = 0;
        __syncthreads();
        #pragma unroll
        for (int i = 0; i < EPTS; ++i) {
            int e = t + i * TPB;
            if (e < NPRED) {
                float s = sci[e];
                if (s != -INFINITY) {
                    unsigned int sb = __float_as_uint(s);
                    int bin = (int)((sb - 0x3E800000u) >> 14);
                    if (bin >= b_lo && bin < b_hi) {
                        int slot = atomicAdd(&s_cnt, 1);
                        if (slot < TCAP)
                            sbuf[slot] = ((unsigned long long)(~sb) << 32) | (unsigned int)e;
                    }
                }
            }
        }
        __syncthreads();
        // ---- bitonic sort ascending: key = (~scorebits, index) ----
        for (int k = 2; k <= TCAP; k <<= 1) {
            for (int j = k >> 1; j > 0; j >>= 1) {
                #pragma unroll
                for (int m = 0; m < SLOTS; ++m) {
                    int i = t + m * TPB;
                    int l = i ^ j;
                    if (l > i) {
                        unsigned long long a = sbuf[i], b = sbuf[l];
                        if ((a > b) == ((i & k) == 0)) { sbuf[i] = b; sbuf[l] = a; }
                    }
                }
                __syncthreads();
            }
        }
        // ---- unpack: thread owns sorted positions t*8 .. t*8+7 ----
        unsigned int amask = 0;
        unsigned int cidx[SLOTS];
        float cx1[SLOTS], cy1[SLOTS], cx2[SLOTS], cy2[SLOTS], car[SLOTS];
        #pragma unroll
        for (int s2 = 0; s2 < SLOTS; ++s2) {
            unsigned long long key = sbuf[t * SLOTS + s2];
            bool al = (key != ~0ULL);
            unsigned int ix = al ? (unsigned int)key : 0u;
            cidx[s2] = ix;
            float4 b = bxi[ix];
            cx1[s2] = b.x; cy1[s2] = b.y; cx2[s2] = b.z; cy2[s2] = b.w;
            car[s2] = __fmul_rn(__fsub_rn(b.z, b.x), __fsub_rn(b.w, b.y));
            if (al) amask |= (1u << s2);
        }
        // ---- phase A: kill vs previously-kept boxes (parallel) ----
        if (amask) {
            for (int kb = 0; kb < kept; ++kb) {
                float4 B = kbox[kb];
                float BA = __fmul_rn(__fsub_rn(B.z, B.x), __fsub_rn(B.w, B.y));
                #pragma unroll
                for (int s2 = 0; s2 < SLOTS; ++s2) {
                    if (amask & (1u << s2)) {
                        float lx = fmaxf(B.x, cx1[s2]), ly = fmaxf(B.y, cy1[s2]);
                        float rx = fminf(B.z, cx2[s2]), ry = fminf(B.w, cy2[s2]);
                        float ww = fmaxf(__fsub_rn(rx, lx), 0.0f);
                        float hh = fmaxf(__fsub_rn(ry, ly), 0.0f);
                        float inter = __fmul_rn(ww, hh);
                        float denom = __fadd_rn(__fsub_rn(__fadd_rn(BA, car[s2]), inter), 1e-9f);
                        if ((double)inter > K * (double)denom) amask &= ~(1u << s2);
                    }
                }
                if (!amask) break;
            }
        }
        // ---- phase B: in-order serial sweep (2 barriers per kept box) ----
        int par = 0;
        for (;;) {
            int lm = amask ? (t * SLOTS + __builtin_ctz(amask)) : 0x7FFFFFFF;
            #pragma unroll
            for (int off = 32; off; off >>= 1) lm = min(lm, __shfl_down(lm, off));
            if ((t & 63) == 0) s_redA[par][wid] = lm;
            __syncthreads();
            int f = s_redA[par][0];
            #pragma unroll
            for (int w = 1; w < NW; ++w) f = min(f, s_redA[par][w]);
            if (f == 0x7FFFFFFF) break;                  // tranche exhausted
            if (t == (f >> 3)) {                         // owner publishes
                #pragma unroll
                for (int s2 = 0; s2 < SLOTS; ++s2) {
                    if (s2 == (f & 7)) {
                        kbox[kept] = make_float4(cx1[s2], cy1[s2], cx2[s2], cy2[s2]);
                        selidx[img * MAXDET + kept] = (int)cidx[s2];
                        float A = car[s2];   // self-inter, same ops as reference
                        float dns = __fadd_rn(__fsub_rn(__fadd_rn(A, A), A), 1e-9f);
                        s_sticky = ((double)A > K * (double)dns) ? 0 : 1;
                        s_stickyIdx = (int)cidx[s2];
                        amask &= ~(1u << s2);
                    }
                }
            }
            __syncthreads();
            if (s_sticky) {
                // reference re-selects this box for every remaining slot
                for (int k2 = kept + 1 + t; k2 < MAXDET; k2 += TPB)
                    selidx[img * MAXDET + k2] = s_stickyIdx;
                kept = MAXDET;
                break;
            }
            float4 B = kbox[kept];
            float BA = __fmul_rn(__fsub_rn(B.z, B.x), __fsub_rn(B.w, B.y));
            if (amask) {
                #pragma unroll
                for (int s2 = 0; s2 < SLOTS; ++s2) {
                    if (amask & (1u << s2)) {
                        float lx = fmaxf(B.x, cx1[s2]), ly = fmaxf(B.y, cy1[s2]);
                        float rx = fminf(B.z, cx2[s2]), ry = fminf(B.w, cy2[s2]);
                        float ww = fmaxf(__fsub_rn(rx, lx), 0.0f);
                        float hh = fmaxf(__fsub_rn(ry, ly), 0.0f);
                        float inter = __fmul_rn(ww, hh);
                        float denom = __fadd_rn(__fsub_rn(__fadd_rn(BA, car[s2]), inter), 1e-9f);
                        if ((double)inter > K * (double)denom) amask &= ~(1u << s2);
                    }
                }
            }
            ++kept;
            if (kept == MAXDET) break;
            par ^= 1;
        }
        o = (int)Ia[b_lo];
        b_hi = b_lo;
    }
    if (t == 0) selcnt[img] = kept;
}

// ---------------------------------------------------------------------------
// Gather: writes every output element (zeros for padding rows — no memset
// needed). conf/cls/obj recomputed from pred with the identical rn ops.
// ---------------------------------------------------------------------------
#define GT 256

__global__ __launch_bounds__(GT)
void gather_kernel(const float* __restrict__ pred,
                   const float4* __restrict__ box,
                   const float* __restrict__ logits,
                   const int* __restrict__ selidx,
                   const int* __restrict__ selcnt,
                   float* __restrict__ out) {
    int tid = blockIdx.x * GT + threadIdx.x;
    if (tid >= BATCH * MAXDET * NDIM) return;
    int row = tid / NDIM, col = tid - row * NDIM;
    int img = row / MAXDET, det = row - img * MAXDET;
    float v = 0.0f;
    if (det < selcnt[img]) {
        int s = selidx[img * MAXDET + det];
        size_t g = (size_t)img * NPRED + s;
        if (col < 4) {
            float4 b = box[g];
            v = (col == 0) ? b.x : (col == 1) ? b.y : (col == 2) ? b.z : b.w;
        } else if (col == 6) {
            v = pred[g * 85 + 4];
        } else if (col >= 7) {
            v = logits[g * NC + (col - 7)];
        } else {
            const float* p = pred + g * 85;
            float obj = p[4];
            float best = -INFINITY; int bc = 0;
            #pragma unroll 8
            for (int c = 0; c < NC; ++c) {
                float q = __fmul_rn(p[5 + c], obj);
                if (q > best) { best = q; bc = c; }
            }
            v = (col == 4) ? best : (float)bc;
        }
    }
    out[tid] = v;
}

extern "C" void kernel_launch(void* const* d_in, const int* in_sizes, int n_in,
                              void* d_out, int out_size, void* d_ws, size_t ws_size,
                              hipStream_t stream) {
    const float* pred   = (const float*)d_in[0];
    const float* logits = (const float*)d_in[1];
    float* out = (float*)d_out;

    char* ws = (char*)d_ws;
    float*  sc     = (float*)ws;                                   // 1,612,800 B
    float4* box    = (float4*)(ws + 1612800);                      // 6,451,200 B
    int*    selidx = (int*)(ws + 1612800 + 6451200);               //    19,200 B
    int*    selcnt = (int*)(ws + 1612800 + 6451200 + 19200);       //        64 B

    prep_kernel<<<BATCH * NPRED / PB, PREP_TPB, 0, stream>>>(pred, sc, box);
    nms_kernel<<<BATCH, TPB, 0, stream>>>(sc, box, selidx, selcnt);
    int gtot = BATCH * MAXDET * NDIM;
    gather_kernel<<<(gtot + GT - 1) / GT, GT, 0, stream>>>(pred, box, logits, selidx, selcnt, out);
}

// Round 6
// 438.086 us; speedup vs baseline: 5.3640x; 1.6788x over previous
//
#include <hip/hip_runtime.h>
#include <math.h>

#define NPRED  25200
#define BATCH  16
#define NC     80
#define MAXDET 300
#define NDIM   87

// ---------------------------------------------------------------------------
// Prep: LDS-staged coalesced loads. All arithmetic unfused-rn to match numpy
// fp32 bit-exactly (selection decisions depend on exact values). Validated.
// ---------------------------------------------------------------------------
#define PREP_TPB 256
#define PB 128

__global__ __launch_bounds__(PREP_TPB)
void prep_kernel(const float* __restrict__ pred,
                 float* __restrict__ sc,
                 float4* __restrict__ box) {
    __shared__ float4 s4[PB * 85 / 4];
    float* s = (float*)s4;
    const int t = threadIdx.x;
    const float4* p4 = (const float4*)(pred + (size_t)blockIdx.x * (PB * 85));
    for (int i = t; i < PB * 85 / 4; i += PREP_TPB) s4[i] = p4[i];
    __syncthreads();
    if (t < PB) {
        const float* row = s + t * 85;
        float x = row[0], y = row[1], w = row[2], h = row[3], obj = row[4];
        float best = -INFINITY;
        #pragma unroll 8
        for (int c = 0; c < NC; ++c) {
            float v = __fmul_rn(row[5 + c], obj);
            if (v > best) best = v;          // strict >: first index on ties
        }
        float hw = __fmul_rn(w, 0.5f), hh = __fmul_rn(h, 0.5f);
        bool valid = (obj > 0.25f) && (best > 0.25f);
        int g = blockIdx.x * PB + t;
        sc[g]  = valid ? best : -INFINITY;
        box[g] = make_float4(__fsub_rn(x, hw), __fsub_rn(y, hh),
                             __fadd_rn(x, hw), __fadd_rn(y, hh));
    }
}

// ---------------------------------------------------------------------------
// NMS via sort-and-sweep, round-6 structure: windowed wave-level sweep.
// Exactly equivalent to repeated argmax+suppress: candidates processed in
// (score desc, index asc) order; kept iff no earlier-kept box IoU>0.45.
// Per tranche (<=4096 cands): 1024-bin histogram window pick -> exact u64
// bitonic sort of (~scorebits, index) -> 64 rounds of:
//   phase-1 (all 512 threads): kill register-resident candidates vs kept
//            boxes added since last round (pure VALU, no barriers inside)
//   sweep  (wave 0 only):      ballot/ctz/shfl serial sweep of the next 64
//            sorted positions — no block barriers per kept box.
// Sticky degenerate case (kept box with self-IoU<=0.45 re-selected forever)
// handled exactly as validated in round 5. IoU decision exact:
// fdiv_rn(i,d) > 0.45f  <=>  (double)i > K*(double)d, K=(double)0.45f+2^-26
// (0.45f mantissa even => midpoint rounds down; 26b x 24b f64 product exact).
// ---------------------------------------------------------------------------
#define TPB    512
#define NBIN   1024
#define TCAP   4096
#define SLOTS  8                  // TCAP / TPB
#define NW     (TPB / 64)         // 8 waves
#define EPTS   ((NPRED + TPB - 1) / TPB)   // 50

__global__ __launch_bounds__(TPB)
void nms_kernel(const float* __restrict__ sc_g,
                const float4* __restrict__ box_g,
                int* __restrict__ selidx,
                int* __restrict__ selcnt) {
    __shared__ unsigned long long sbuf[TCAP];   // 32 KB: sort keys / wave hists
    __shared__ unsigned int scanA[NBIN];        // 4 KB
    __shared__ unsigned int scanB[NBIN];        // 4 KB
    __shared__ float4 kbox[MAXDET];             // 4.8 KB
    __shared__ int s_alive[TCAP];               // 16 KB
    __shared__ int s_redB[NW];
    __shared__ int s_kept, s_sticky, s_stickyIdx, s_fillFrom, s_cnt;

    const int img = blockIdx.x, t = threadIdx.x, wid = t >> 6;
    const float*  sci = sc_g  + (size_t)img * NPRED;
    const float4* bxi = box_g + (size_t)img * NPRED;
    const double K = (double)0.45f + 0x1p-26;

    // ---- histogram: NW per-wave copies overlaid on sbuf, then reduce ----
    unsigned int (*whist)[NBIN] = (unsigned int (*)[NBIN])sbuf;
    for (int i = t; i < NW * NBIN; i += TPB) ((unsigned int*)sbuf)[i] = 0u;
    __syncthreads();
    for (int i = 0; i < EPTS; ++i) {
        int e = t + i * TPB;
        if (e < NPRED) {
            float s = sci[e];
            if (s != -INFINITY) {
                unsigned int sb = __float_as_uint(s);
                atomicAdd(&whist[wid][(sb - 0x3E800000u) >> 14], 1u);
            }
        }
    }
    __syncthreads();
    for (int b = t; b < NBIN; b += TPB) {
        unsigned int cs = 0;
        #pragma unroll
        for (int w = 0; w < NW; ++w) cs += whist[w][b];
        scanA[b] = cs;
    }
    __syncthreads();
    // ---- inclusive suffix-sum I[b] = sum_{b'>=b} cnt[b'] (ping-pong) ----
    {
        unsigned int* src = scanA; unsigned int* dst = scanB;
        for (int d = 1; d < NBIN; d <<= 1) {
            for (int b = t; b < NBIN; b += TPB)
                dst[b] = src[b] + ((b + d) < NBIN ? src[b + d] : 0u);
            __syncthreads();
            unsigned int* tmp = src; src = dst; dst = tmp;
        }
    }
    unsigned int* Ia = scanA;              // 10 swaps (even) -> scanA
    int n_valid = (int)Ia[0];
    if (t == 0) { s_kept = 0; s_sticky = 0; }
    __syncthreads();

    int o = 0, b_hi = NBIN;
    for (;;) {
        if (s_kept >= MAXDET || s_sticky || o >= n_valid) break;   // uniform

        // ---- pick bin range [b_lo, b_hi): largest window <= TCAP ----
        int vb = 0x7FFFFFFF;
        #pragma unroll
        for (int bb = 0; bb < NBIN / TPB; ++bb) {
            int b = t + bb * TPB;
            if (b < b_hi && ((int)Ia[b] - o) <= TCAP) vb = min(vb, b);
        }
        #pragma unroll
        for (int off = 32; off; off >>= 1) vb = min(vb, __shfl_down(vb, off));
        if ((t & 63) == 0) s_redB[wid] = vb;
        __syncthreads();
        int b_lo = s_redB[0];
        #pragma unroll
        for (int w = 1; w < NW; ++w) b_lo = min(b_lo, s_redB[w]);
        int c;
        if (b_lo == 0x7FFFFFFF) {
            // pathological: single bin > TCAP; take highest nonempty, clamped
            __syncthreads();
            int vb2 = 0x7FFFFFFF;
            #pragma unroll
            for (int bb = 0; bb < NBIN / TPB; ++bb) {
                int b = t + bb * TPB;
                if (b < b_hi && ((int)Ia[b] - o) > 0) vb2 = min(vb2, -b);
            }
            #pragma unroll
            for (int off = 32; off; off >>= 1) vb2 = min(vb2, __shfl_down(vb2, off));
            if ((t & 63) == 0) s_redB[wid] = vb2;
            __syncthreads();
            int m2 = s_redB[0];
            #pragma unroll
            for (int w = 1; w < NW; ++w) m2 = min(m2, s_redB[w]);
            b_lo = -m2;
            c = min((int)Ia[b_lo] - o, TCAP);
        } else {
            c = (int)Ia[b_lo] - o;
        }
        if (c <= 0) break;

        // ---- pad + scatter tranche candidates (order fixed by sort) ----
        for (int p = t; p < TCAP; p += TPB) sbuf[p] = ~0ULL;
        if (t == 0) s_cnt = 0;
        __syncthreads();
        for (int i = 0; i < EPTS; ++i) {
            int e = t + i * TPB;
            if (e < NPRED) {
                float s = sci[e];
                if (s != -INFINITY) {
                    unsigned int sb = __float_as_uint(s);
                    int bin = (int)((sb - 0x3E800000u) >> 14);
                    if (bin >= b_lo && bin < b_hi) {
                        int slot = atomicAdd(&s_cnt, 1);
                        if (slot < TCAP)
                            sbuf[slot] = ((unsigned long long)(~sb) << 32) | (unsigned int)e;
                    }
                }
            }
        }
        __syncthreads();
        // ---- bitonic sort ascending: key = (~scorebits, index) ----
        for (int k = 2; k <= TCAP; k <<= 1) {
            for (int j = k >> 1; j > 0; j >>= 1) {
                #pragma unroll
                for (int m = 0; m < SLOTS; ++m) {
                    int i = t + m * TPB;
                    int l = i ^ j;
                    if (l > i) {
                        unsigned long long a = sbuf[i], b2 = sbuf[l];
                        if ((a > b2) == ((i & k) == 0)) { sbuf[i] = b2; sbuf[l] = a; }
                    }
                }
                __syncthreads();
            }
        }
        // ---- unpack: thread t owns sorted positions 8t..8t+7 (all within
        //      window t/8). Boxes into registers; alive init into LDS. ----
        unsigned int rm = 0;
        float rx1[SLOTS], ry1[SLOTS], rx2[SLOTS], ry2[SLOTS], rar[SLOTS];
        #pragma unroll
        for (int s = 0; s < SLOTS; ++s) {
            int p = t * SLOTS + s;
            int av = (p < c) ? 1 : 0;          // sort puts real keys first
            unsigned int ix = av ? (unsigned int)sbuf[p] : 0u;
            float4 b = bxi[ix];
            rx1[s] = b.x; ry1[s] = b.y; rx2[s] = b.z; ry2[s] = b.w;
            rar[s] = __fmul_rn(__fsub_rn(b.z, b.x), __fsub_rn(b.w, b.y));
            if (av) rm |= (1u << s);
            s_alive[p] = av;
        }
        __syncthreads();

        const int nwin = (c + 63) >> 6;
        int applied = 0;                        // tranche start: apply ALL kept
        for (int g = 0; g < nwin; ++g) {
            int k0 = s_kept;                    // uniform (post-barrier)
            // ---- phase-1: kill my register candidates vs kept [applied,k0) ----
            if (rm) {
                for (int kb = applied; kb < k0; ++kb) {
                    float4 B = kbox[kb];
                    float BA = __fmul_rn(__fsub_rn(B.z, B.x), __fsub_rn(B.w, B.y));
                    #pragma unroll
                    for (int s = 0; s < SLOTS; ++s) {
                        if (rm & (1u << s)) {
                            float lx = fmaxf(B.x, rx1[s]), ly = fmaxf(B.y, ry1[s]);
                            float rx = fminf(B.z, rx2[s]), ry = fminf(B.w, ry2[s]);
                            float ww = fmaxf(__fsub_rn(rx, lx), 0.0f);
                            float hh = fmaxf(__fsub_rn(ry, ly), 0.0f);
                            float inter = __fmul_rn(ww, hh);
                            float denom = __fadd_rn(__fsub_rn(__fadd_rn(BA, rar[s]), inter), 1e-9f);
                            if ((double)inter > K * (double)denom) {
                                rm &= ~(1u << s);
                                s_alive[t * SLOTS + s] = 0;
                            }
                        }
                    }
                    if (!rm) break;
                }
            }
            applied = k0;
            __syncthreads();
            // ---- sweep window g: wave 0 only, no block barriers inside ----
            if (t < 64) {
                int p = g * 64 + t;
                int a = s_alive[p];
                unsigned int ix = a ? (unsigned int)sbuf[p] : 0u;
                float4 b = bxi[ix];
                float cx1 = b.x, cy1 = b.y, cx2 = b.z, cy2 = b.w;
                float car = __fmul_rn(__fsub_rn(b.z, b.x), __fsub_rn(b.w, b.y));
                int kept = k0;
                for (;;) {
                    unsigned long long bal = __ballot(a != 0);
                    if (!bal) break;
                    int f = (int)__builtin_ctzll(bal);
                    float Bx1 = __shfl(cx1, f), By1 = __shfl(cy1, f);
                    float Bx2 = __shfl(cx2, f), By2 = __shfl(cy2, f);
                    float BA  = __shfl(car, f);
                    int bidx  = __shfl((int)ix, f);
                    if (t == f) a = 0;
                    if (t == 0) {
                        selidx[img * MAXDET + kept] = bidx;
                        kbox[kept] = make_float4(Bx1, By1, Bx2, By2);
                    }
                    // sticky check: reference-exact self-IoU
                    float dns = __fadd_rn(__fsub_rn(__fadd_rn(BA, BA), BA), 1e-9f);
                    if (!((double)BA > K * (double)dns)) {
                        if (t == 0) { s_sticky = 1; s_stickyIdx = bidx; s_fillFrom = kept + 1; }
                        kept = MAXDET;
                        break;
                    }
                    if (a) {
                        float lx = fmaxf(Bx1, cx1), ly = fmaxf(By1, cy1);
                        float rx = fminf(Bx2, cx2), ry = fminf(By2, cy2);
                        float ww = fmaxf(__fsub_rn(rx, lx), 0.0f);
                        float hh = fmaxf(__fsub_rn(ry, ly), 0.0f);
                        float inter = __fmul_rn(ww, hh);
                        float denom = __fadd_rn(__fsub_rn(__fadd_rn(BA, car), inter), 1e-9f);
                        if ((double)inter > K * (double)denom) a = 0;
                    }
                    ++kept;
                    if (kept >= MAXDET) break;
                }
                if (t == 0) s_kept = kept;
            }
            __syncthreads();
            if ((t >> 3) == g) rm = 0;          // my window fully swept
            if (s_kept >= MAXDET || s_sticky) break;   // uniform post-barrier
        }
        o = (int)Ia[b_lo];
        b_hi = b_lo;
    }
    // ---- finalize ----
    int keptF = s_kept;
    if (s_sticky) {
        for (int k2 = s_fillFrom + t; k2 < MAXDET; k2 += TPB)
            selidx[img * MAXDET + k2] = s_stickyIdx;
        keptF = MAXDET;
    }
    if (t == 0) selcnt[img] = keptF;
}

// ---------------------------------------------------------------------------
// Gather: writes every output element (zeros for padding rows — no memset
// needed). conf/cls/obj recomputed from pred with the identical rn ops.
// ---------------------------------------------------------------------------
#define GT 256

__global__ __launch_bounds__(GT)
void gather_kernel(const float* __restrict__ pred,
                   const float4* __restrict__ box,
                   const float* __restrict__ logits,
                   const int* __restrict__ selidx,
                   const int* __restrict__ selcnt,
                   float* __restrict__ out) {
    int tid = blockIdx.x * GT + threadIdx.x;
    if (tid >= BATCH * MAXDET * NDIM) return;
    int row = tid / NDIM, col = tid - row * NDIM;
    int img = row / MAXDET, det = row - img * MAXDET;
    float v = 0.0f;
    if (det < selcnt[img]) {
        int s = selidx[img * MAXDET + det];
        size_t g = (size_t)img * NPRED + s;
        if (col < 4) {
            float4 b = box[g];
            v = (col == 0) ? b.x : (col == 1) ? b.y : (col == 2) ? b.z : b.w;
        } else if (col == 6) {
            v = pred[g * 85 + 4];
        } else if (col >= 7) {
            v = logits[g * NC + (col - 7)];
        } else {
            const float* p = pred + g * 85;
            float obj = p[4];
            float best = -INFINITY; int bc = 0;
            #pragma unroll 8
            for (int c = 0; c < NC; ++c) {
                float q = __fmul_rn(p[5 + c], obj);
                if (q > best) { best = q; bc = c; }
            }
            v = (col == 4) ? best : (float)bc;
        }
    }
    out[tid] = v;
}

extern "C" void kernel_launch(void* const* d_in, const int* in_sizes, int n_in,
                              void* d_out, int out_size, void* d_ws, size_t ws_size,
                              hipStream_t stream) {
    const float* pred   = (const float*)d_in[0];
    const float* logits = (const float*)d_in[1];
    float* out = (float*)d_out;

    char* ws = (char*)d_ws;
    float*  sc     = (float*)ws;                                   // 1,612,800 B
    float4* box    = (float4*)(ws + 1612800);                      // 6,451,200 B
    int*    selidx = (int*)(ws + 1612800 + 6451200);               //    19,200 B
    int*    selcnt = (int*)(ws + 1612800 + 6451200 + 19200);       //        64 B

    prep_kernel<<<BATCH * NPRED / PB, PREP_TPB, 0, stream>>>(pred, sc, box);
    nms_kernel<<<BATCH, TPB, 0, stream>>>(sc, box, selidx, selcnt);
    int gtot = BATCH * MAXDET * NDIM;
    gather_kernel<<<(gtot + GT - 1) / GT, GT, 0, stream>>>(pred, box, logits, selidx, selcnt, out);
}

// Round 7
// 392.726 us; speedup vs baseline: 5.9835x; 1.1155x over previous
//
#include <hip/hip_runtime.h>
#include <math.h>

#define NPRED  25200
#define BATCH  16
#define NC     80
#define MAXDET 300
#define NDIM   87

// ---------------------------------------------------------------------------
// Prep: LDS-staged coalesced loads. All arithmetic unfused-rn to match numpy
// fp32 bit-exactly (selection decisions depend on exact values). Validated.
// ---------------------------------------------------------------------------
#define PREP_TPB 256
#define PB 128

__global__ __launch_bounds__(PREP_TPB)
void prep_kernel(const float* __restrict__ pred,
                 float* __restrict__ sc,
                 float4* __restrict__ box) {
    __shared__ float4 s4[PB * 85 / 4];
    float* s = (float*)s4;
    const int t = threadIdx.x;
    const float4* p4 = (const float4*)(pred + (size_t)blockIdx.x * (PB * 85));
    for (int i = t; i < PB * 85 / 4; i += PREP_TPB) s4[i] = p4[i];
    __syncthreads();
    if (t < PB) {
        const float* row = s + t * 85;
        float x = row[0], y = row[1], w = row[2], h = row[3], obj = row[4];
        float best = -INFINITY;
        #pragma unroll 8
        for (int c = 0; c < NC; ++c) {
            float v = __fmul_rn(row[5 + c], obj);
            if (v > best) best = v;          // strict >: first index on ties
        }
        float hw = __fmul_rn(w, 0.5f), hh = __fmul_rn(h, 0.5f);
        bool valid = (obj > 0.25f) && (best > 0.25f);
        int g = blockIdx.x * PB + t;
        sc[g]  = valid ? best : -INFINITY;
        box[g] = make_float4(__fsub_rn(x, hw), __fsub_rn(y, hh),
                             __fadd_rn(x, hw), __fadd_rn(y, hh));
    }
}

// ---------------------------------------------------------------------------
// NMS sort-and-sweep, round-7: bulk-pre-kill + survivor compaction.
// Exactly equivalent to repeated argmax+suppress: candidates processed in
// (score desc, index asc) order; kept iff no earlier-kept box IoU>0.45.
// Round-7 deltas vs validated round 6:
//  - tranche candidates are killed vs ALL kept-so-far boxes BEFORE sorting
//    (kills commute; the sort re-establishes exact order), survivors
//    compacted to the front -> sort size = next_pow2(survivors), and
//    window count = ceil(survivors/64) instead of 64.
//  - first tranche capped at 1024 (cheap head sort), later tranches 4096,
//    with a TCAP fallback pick if no <=1024 window exists.
//  - bin index clamped to NBIN-1 (conf rounding to 1.0f hardening).
// Sticky degenerate case (kept box with self-IoU<=0.45 re-selected forever)
// handled exactly as validated. IoU decision exact:
// fdiv_rn(i,d) > 0.45f  <=>  (double)i > K*(double)d, K=(double)0.45f+2^-26
// (0.45f mantissa even => midpoint rounds down; 26b x 24b f64 product exact).
// ---------------------------------------------------------------------------
#define TPB      512
#define NBIN     1024
#define TCAP     4096
#define FIRSTCAP 1024
#define SLOTS    8                  // TCAP / TPB
#define NW       (TPB / 64)         // 8 waves
#define EPTS     ((NPRED + TPB - 1) / TPB)   // 50

__device__ __forceinline__ bool iou_gt(float Bx1, float By1, float Bx2, float By2,
                                       float BA,
                                       float cx1, float cy1, float cx2, float cy2,
                                       float ca, double K) {
    float lx = fmaxf(Bx1, cx1), ly = fmaxf(By1, cy1);
    float rx = fminf(Bx2, cx2), ry = fminf(By2, cy2);
    float ww = fmaxf(__fsub_rn(rx, lx), 0.0f);
    float hh = fmaxf(__fsub_rn(ry, ly), 0.0f);
    float inter = __fmul_rn(ww, hh);
    float denom = __fadd_rn(__fsub_rn(__fadd_rn(BA, ca), inter), 1e-9f);
    return ((double)inter > K * (double)denom);
}

__device__ __forceinline__ int blk_min(int v, int* s_red, int t, int wid) {
    #pragma unroll
    for (int off = 32; off; off >>= 1) v = min(v, __shfl_down(v, off));
    if ((t & 63) == 0) s_red[wid] = v;
    __syncthreads();
    int r = s_red[0];
    #pragma unroll
    for (int w = 1; w < NW; ++w) r = min(r, s_red[w]);
    return r;
}

__global__ __launch_bounds__(TPB, 2)
void nms_kernel(const float* __restrict__ sc_g,
                const float4* __restrict__ box_g,
                int* __restrict__ selidx,
                int* __restrict__ selcnt) {
    __shared__ unsigned long long sbuf[TCAP];   // 32 KB: sort keys / wave hists
    __shared__ unsigned int scanA[NBIN];        // 4 KB
    __shared__ unsigned int scanB[NBIN];        // 4 KB
    __shared__ float4 kbox[MAXDET];             // 4.8 KB
    __shared__ unsigned char s_alive[TCAP];     // 4 KB (byte per slot, owner-written)
    __shared__ int s_red[NW];
    __shared__ int s_kept, s_sticky, s_stickyIdx, s_fillFrom, s_cnt, s_cnt2;

    const int img = blockIdx.x, t = threadIdx.x, wid = t >> 6;
    const float*  sci = sc_g  + (size_t)img * NPRED;
    const float4* bxi = box_g + (size_t)img * NPRED;
    const double K = (double)0.45f + 0x1p-26;

    // ---- histogram: NW per-wave copies overlaid on sbuf, then reduce ----
    unsigned int (*whist)[NBIN] = (unsigned int (*)[NBIN])sbuf;
    for (int i = t; i < NW * NBIN; i += TPB) ((unsigned int*)sbuf)[i] = 0u;
    __syncthreads();
    for (int i = 0; i < EPTS; ++i) {
        int e = t + i * TPB;
        if (e < NPRED) {
            float s = sci[e];
            if (s != -INFINITY) {
                unsigned int sb = __float_as_uint(s);
                int bin = min((int)((sb - 0x3E800000u) >> 14), NBIN - 1);
                atomicAdd(&whist[wid][bin], 1u);
            }
        }
    }
    __syncthreads();
    for (int b = t; b < NBIN; b += TPB) {
        unsigned int cs = 0;
        #pragma unroll
        for (int w = 0; w < NW; ++w) cs += whist[w][b];
        scanA[b] = cs;
    }
    __syncthreads();
    // ---- inclusive suffix-sum I[b] = sum_{b'>=b} cnt[b'] (ping-pong) ----
    {
        unsigned int* src = scanA; unsigned int* dst = scanB;
        for (int d = 1; d < NBIN; d <<= 1) {
            for (int b = t; b < NBIN; b += TPB)
                dst[b] = src[b] + ((b + d) < NBIN ? src[b + d] : 0u);
            __syncthreads();
            unsigned int* tmp = src; src = dst; dst = tmp;
        }
    }
    unsigned int* Ia = scanA;              // 10 swaps (even) -> scanA
    int n_valid = (int)Ia[0];
    if (t == 0) { s_kept = 0; s_sticky = 0; }
    __syncthreads();

    int o = 0, b_hi = NBIN;
    bool firstT = true;
    for (;;) {
        if (s_kept >= MAXDET || s_sticky || o >= n_valid) break;   // uniform

        // ---- pick bin range [b_lo, b_hi): largest window <= cap ----
        const int cap = firstT ? FIRSTCAP : TCAP;
        __syncthreads();
        int vb = 0x7FFFFFFF;
        #pragma unroll
        for (int bb = 0; bb < NBIN; bb += TPB) {
            int b = t + bb;
            if (b < b_hi && ((int)Ia[b] - o) <= cap) vb = min(vb, b);
        }
        int b_lo = blk_min(vb, s_red, t, wid);
        if (b_lo == 0x7FFFFFFF && cap != TCAP) {     // fallback: full cap
            __syncthreads();
            vb = 0x7FFFFFFF;
            #pragma unroll
            for (int bb = 0; bb < NBIN; bb += TPB) {
                int b = t + bb;
                if (b < b_hi && ((int)Ia[b] - o) <= TCAP) vb = min(vb, b);
            }
            b_lo = blk_min(vb, s_red, t, wid);
        }
        int c;
        if (b_lo != 0x7FFFFFFF) {
            c = (int)Ia[b_lo] - o;
        } else {
            // pathological: single bin > TCAP; take highest nonempty, clamped
            __syncthreads();
            vb = 0x7FFFFFFF;
            #pragma unroll
            for (int bb = 0; bb < NBIN; bb += TPB) {
                int b = t + bb;
                if (b < b_hi && ((int)Ia[b] - o) > 0) vb = min(vb, -b);
            }
            int m2 = blk_min(vb, s_red, t, wid);
            b_lo = -m2;
            c = min((int)Ia[b_lo] - o, TCAP);
        }
        if (c <= 0) break;

        // ---- scatter tranche candidates (unordered; sort fixes order) ----
        if (t == 0) { s_cnt = 0; s_cnt2 = 0; }
        __syncthreads();
        for (int i = 0; i < EPTS; ++i) {
            int e = t + i * TPB;
            if (e < NPRED) {
                float s = sci[e];
                if (s != -INFINITY) {
                    unsigned int sb = __float_as_uint(s);
                    int bin = min((int)((sb - 0x3E800000u) >> 14), NBIN - 1);
                    if (bin >= b_lo && bin < b_hi) {
                        int slot = atomicAdd(&s_cnt, 1);
                        if (slot < TCAP)
                            sbuf[slot] = ((unsigned long long)(~sb) << 32) | (unsigned int)e;
                    }
                }
            }
        }
        __syncthreads();

        // ---- bulk-kill vs ALL kept-so-far (kills commute; order restored
        //      by the sort), then compact survivors to the front ----
        unsigned int um = 0;
        unsigned long long ukey[SLOTS];
        #pragma unroll
        for (int s = 0; s < SLOTS; ++s) {
            int p = t * SLOTS + s;
            bool av = (p < c);
            ukey[s] = av ? sbuf[p] : ~0ULL;
            if (av) um |= (1u << s);
        }
        __syncthreads();                   // all sbuf reads complete
        const int kept0 = s_kept;          // uniform
        if (kept0 > 0) {
            if (um) {
                float ux1[SLOTS], uy1[SLOTS], ux2[SLOTS], uy2[SLOTS], uar[SLOTS];
                #pragma unroll
                for (int s = 0; s < SLOTS; ++s) {
                    unsigned int ix = (um & (1u << s)) ? (unsigned int)ukey[s] : 0u;
                    float4 b = bxi[ix];
                    ux1[s] = b.x; uy1[s] = b.y; ux2[s] = b.z; uy2[s] = b.w;
                    uar[s] = __fmul_rn(__fsub_rn(b.z, b.x), __fsub_rn(b.w, b.y));
                }
                for (int kb = 0; kb < kept0; ++kb) {
                    float4 B = kbox[kb];
                    float BA = __fmul_rn(__fsub_rn(B.z, B.x), __fsub_rn(B.w, B.y));
                    #pragma unroll
                    for (int s = 0; s < SLOTS; ++s) {
                        if (um & (1u << s)) {
                            if (iou_gt(B.x, B.y, B.z, B.w, BA,
                                       ux1[s], uy1[s], ux2[s], uy2[s], uar[s], K))
                                um &= ~(1u << s);
                        }
                    }
                    if (!um) break;
                }
            }
            #pragma unroll
            for (int s = 0; s < SLOTS; ++s)
                if (um & (1u << s)) {
                    int sl = atomicAdd(&s_cnt2, 1);
                    sbuf[sl] = ukey[s];
                }
        }
        __syncthreads();
        const int cnt2 = (kept0 == 0) ? c : s_cnt2;   // uniform

        if (cnt2 > 0) {
            // ---- pad to power of two; bitonic sort ascending over
            //      (~scorebits, index) => score desc, index asc ----
            int m = 1; while (m < cnt2) m <<= 1;
            for (int p = t; p < m; p += TPB) if (p >= cnt2) sbuf[p] = ~0ULL;
            __syncthreads();
            for (int k = 2; k <= m; k <<= 1) {
                for (int j = k >> 1; j > 0; j >>= 1) {
                    for (int i = t; i < m; i += TPB) {
                        int l = i ^ j;
                        if (l > i) {
                            unsigned long long a = sbuf[i], b2 = sbuf[l];
                            if ((a > b2) == ((i & k) == 0)) { sbuf[i] = b2; sbuf[l] = a; }
                        }
                    }
                    __syncthreads();
                }
            }
            // ---- unpack: thread t owns sorted positions 8t..8t+7 ----
            unsigned int rm = 0;
            unsigned int cidx[SLOTS];
            float rx1[SLOTS], ry1[SLOTS], rx2[SLOTS], ry2[SLOTS], rar[SLOTS];
            #pragma unroll
            for (int s = 0; s < SLOTS; ++s) {
                int p = t * SLOTS + s;
                bool av = (p < cnt2);
                unsigned int ix = av ? (unsigned int)sbuf[p] : 0u;
                cidx[s] = ix;
                float4 b = bxi[ix];
                rx1[s] = b.x; ry1[s] = b.y; rx2[s] = b.z; ry2[s] = b.w;
                rar[s] = __fmul_rn(__fsub_rn(b.z, b.x), __fsub_rn(b.w, b.y));
                if (av) rm |= (1u << s);
                s_alive[p] = av ? 1 : 0;
            }
            __syncthreads();

            const int nwin = (cnt2 + 63) >> 6;
            int applied = kept0;           // bulk-kill already covered [0,kept0)
            for (int g = 0; g < nwin; ++g) {
                int k0 = s_kept;           // uniform (post-barrier)
                // ---- phase-1: kill my register candidates vs kept [applied,k0) ----
                if (rm) {
                    for (int kb = applied; kb < k0; ++kb) {
                        float4 B = kbox[kb];
                        float BA = __fmul_rn(__fsub_rn(B.z, B.x), __fsub_rn(B.w, B.y));
                        #pragma unroll
                        for (int s = 0; s < SLOTS; ++s) {
                            if (rm & (1u << s)) {
                                if (iou_gt(B.x, B.y, B.z, B.w, BA,
                                           rx1[s], ry1[s], rx2[s], ry2[s], rar[s], K)) {
                                    rm &= ~(1u << s);
                                    s_alive[t * SLOTS + s] = 0;
                                }
                            }
                        }
                        if (!rm) break;
                    }
                }
                applied = k0;
                __syncthreads();
                // ---- sweep window g: wave 0 only, no block barriers inside ----
                if (t < 64) {
                    int p = g * 64 + t;
                    int a = s_alive[p];
                    unsigned int ix = a ? (unsigned int)sbuf[p] : 0u;
                    float4 b = bxi[ix];
                    float cx1 = b.x, cy1 = b.y, cx2 = b.z, cy2 = b.w;
                    float car = __fmul_rn(__fsub_rn(b.z, b.x), __fsub_rn(b.w, b.y));
                    int kept = k0;
                    for (;;) {
                        unsigned long long bal = __ballot(a != 0);
                        if (!bal) break;
                        int f = (int)__builtin_ctzll(bal);
                        float Bx1 = __shfl(cx1, f), By1 = __shfl(cy1, f);
                        float Bx2 = __shfl(cx2, f), By2 = __shfl(cy2, f);
                        float BA  = __shfl(car, f);
                        int bidx  = __shfl((int)ix, f);
                        if (t == f) a = 0;
                        if (t == 0) {
                            selidx[img * MAXDET + kept] = bidx;
                            kbox[kept] = make_float4(Bx1, By1, Bx2, By2);
                        }
                        // sticky check: reference-exact self-IoU
                        float dns = __fadd_rn(__fsub_rn(__fadd_rn(BA, BA), BA), 1e-9f);
                        if (!((double)BA > K * (double)dns)) {
                            if (t == 0) { s_sticky = 1; s_stickyIdx = bidx; s_fillFrom = kept + 1; }
                            kept = MAXDET;
                            break;
                        }
                        if (a) {
                            if (iou_gt(Bx1, By1, Bx2, By2, BA,
                                       cx1, cy1, cx2, cy2, car, K)) a = 0;
                        }
                        ++kept;
                        if (kept >= MAXDET) break;
                    }
                    if (t == 0) s_kept = kept;
                }
                __syncthreads();
                if ((t >> 3) == g) rm = 0;            // my window fully swept
                if (s_kept >= MAXDET || s_sticky) break;   // uniform post-barrier
            }
        }
        o = (int)Ia[b_lo];
        b_hi = b_lo;
        firstT = false;
    }
    // ---- finalize ----
    int keptF = s_kept;
    if (s_sticky) {
        for (int k2 = s_fillFrom + t; k2 < MAXDET; k2 += TPB)
            selidx[img * MAXDET + k2] = s_stickyIdx;
        keptF = MAXDET;
    }
    if (t == 0) selcnt[img] = keptF;
}

// ---------------------------------------------------------------------------
// Gather: writes every output element (zeros for padding rows — no memset
// needed). conf/cls/obj recomputed from pred with the identical rn ops.
// ---------------------------------------------------------------------------
#define GT 256

__global__ __launch_bounds__(GT)
void gather_kernel(const float* __restrict__ pred,
                   const float4* __restrict__ box,
                   const float* __restrict__ logits,
                   const int* __restrict__ selidx,
                   const int* __restrict__ selcnt,
                   float* __restrict__ out) {
    int tid = blockIdx.x * GT + threadIdx.x;
    if (tid >= BATCH * MAXDET * NDIM) return;
    int row = tid / NDIM, col = tid - row * NDIM;
    int img = row / MAXDET, det = row - img * MAXDET;
    float v = 0.0f;
    if (det < selcnt[img]) {
        int s = selidx[img * MAXDET + det];
        size_t g = (size_t)img * NPRED + s;
        if (col < 4) {
            float4 b = box[g];
            v = (col == 0) ? b.x : (col == 1) ? b.y : (col == 2) ? b.z : b.w;
        } else if (col == 6) {
            v = pred[g * 85 + 4];
        } else if (col >= 7) {
            v = logits[g * NC + (col - 7)];
        } else {
            const float* p = pred + g * 85;
            float obj = p[4];
            float best = -INFINITY; int bc = 0;
            #pragma unroll 8
            for (int c = 0; c < NC; ++c) {
                float q = __fmul_rn(p[5 + c], obj);
                if (q > best) { best = q; bc = c; }
            }
            v = (col == 4) ? best : (float)bc;
        }
    }
    out[tid] = v;
}

extern "C" void kernel_launch(void* const* d_in, const int* in_sizes, int n_in,
                              void* d_out, int out_size, void* d_ws, size_t ws_size,
                              hipStream_t stream) {
    const float* pred   = (const float*)d_in[0];
    const float* logits = (const float*)d_in[1];
    float* out = (float*)d_out;

    char* ws = (char*)d_ws;
    float*  sc     = (float*)ws;                                   // 1,612,800 B
    float4* box    = (float4*)(ws + 1612800);                      // 6,451,200 B
    int*    selidx = (int*)(ws + 1612800 + 6451200);               //    19,200 B
    int*    selcnt = (int*)(ws + 1612800 + 6451200 + 19200);       //        64 B

    prep_kernel<<<BATCH * NPRED / PB, PREP_TPB, 0, stream>>>(pred, sc, box);
    nms_kernel<<<BATCH, TPB, 0, stream>>>(sc, box, selidx, selcnt);
    int gtot = BATCH * MAXDET * NDIM;
    gather_kernel<<<(gtot + GT - 1) / GT, GT, 0, stream>>>(pred, box, logits, selidx, selcnt, out);
}

// Round 8
// 303.828 us; speedup vs baseline: 7.7343x; 1.2926x over previous
//
#include <hip/hip_runtime.h>
#include <math.h>

#define NPRED  25200
#define BATCH  16
#define NC     80
#define MAXDET 300
#define NDIM   87
#define NBIN   1024

// ---------------------------------------------------------------------------
// Workspace layout (bytes)
// ---------------------------------------------------------------------------
#define WS_SC      0                      // 16*25200*4   = 1,612,800
#define WS_BOX     1612800                // 16*25200*16  = 6,451,200
#define WS_SELIDX  8064000                // 16*300*4     = 19,200
#define WS_SELCNT  8083200                // 64
#define WS_HIST    8083264                // 16*1024*4    = 65,536
#define WS_CURSOR  8148800                // 65,536
#define WS_IA      8214336                // 65,536
#define WS_BINNED  8279872                // 16*25200*8   = 3,225,600

// ---------------------------------------------------------------------------
// Prep: LDS-staged coalesced loads; also builds the per-image score-bin
// histogram (global atomics). All arithmetic unfused-rn to match numpy fp32
// bit-exactly (selection decisions depend on exact values). Validated core.
// ---------------------------------------------------------------------------
#define PREP_TPB 256
#define PB 128

__global__ __launch_bounds__(PREP_TPB)
void prep_kernel(const float* __restrict__ pred,
                 float* __restrict__ sc,
                 float4* __restrict__ box,
                 unsigned int* __restrict__ hist) {
    __shared__ float4 s4[PB * 85 / 4];
    float* s = (float*)s4;
    const int t = threadIdx.x;
    const float4* p4 = (const float4*)(pred + (size_t)blockIdx.x * (PB * 85));
    for (int i = t; i < PB * 85 / 4; i += PREP_TPB) s4[i] = p4[i];
    __syncthreads();
    if (t < PB) {
        const float* row = s + t * 85;
        float x = row[0], y = row[1], w = row[2], h = row[3], obj = row[4];
        float best = -INFINITY;
        #pragma unroll 8
        for (int c = 0; c < NC; ++c) {
            float v = __fmul_rn(row[5 + c], obj);
            if (v > best) best = v;          // strict >: first index on ties
        }
        float hw = __fmul_rn(w, 0.5f), hh = __fmul_rn(h, 0.5f);
        bool valid = (obj > 0.25f) && (best > 0.25f);
        int g = blockIdx.x * PB + t;
        sc[g]  = valid ? best : -INFINITY;
        box[g] = make_float4(__fsub_rn(x, hw), __fsub_rn(y, hh),
                             __fadd_rn(x, hw), __fadd_rn(y, hh));
        if (valid) {
            int img = g / NPRED;
            unsigned int sb = __float_as_uint(best);
            int bin = min((int)((sb - 0x3E800000u) >> 14), NBIN - 1);
            atomicAdd(&hist[img * NBIN + bin], 1u);
        }
    }
}

// ---------------------------------------------------------------------------
// Scan: per-image inclusive suffix-sum Ia[b] = sum_{b'>=b} cnt[b'] and
// per-bin scatter cursors (bin b occupies [Ia[b]-cnt[b], Ia[b]) ).
// ---------------------------------------------------------------------------
__global__ __launch_bounds__(NBIN)
void scan_kernel(const unsigned int* __restrict__ hist,
                 unsigned int* __restrict__ IaG,
                 unsigned int* __restrict__ cursor) {
    __shared__ unsigned int sA[NBIN], sB[NBIN];
    const int img = blockIdx.x, t = threadIdx.x;
    unsigned int cnt = hist[img * NBIN + t];
    sA[t] = cnt;
    __syncthreads();
    unsigned int *src = sA, *dst = sB;
    for (int d = 1; d < NBIN; d <<= 1) {
        dst[t] = src[t] + ((t + d) < NBIN ? src[t + d] : 0u);
        __syncthreads();
        unsigned int* tmp = src; src = dst; dst = tmp;
    }
    // 10 swaps (even) -> result in sA
    IaG[img * NBIN + t]    = src[t];
    cursor[img * NBIN + t] = src[t] - cnt;
}

// ---------------------------------------------------------------------------
// Scatter: counting-sort candidates by bin into the binned array (u64 key =
// (~scorebits, index)). Within-bin order arbitrary; the per-tranche bitonic
// sort re-establishes the exact (score desc, index asc) order.
// ---------------------------------------------------------------------------
#define SCB  16
#define STPB 512

__global__ __launch_bounds__(STPB)
void scatter_kernel(const float* __restrict__ sc,
                    unsigned int* __restrict__ cursor,
                    unsigned long long* __restrict__ binned) {
    const int img = blockIdx.x / SCB, part = blockIdx.x % SCB;
    const float* sci = sc + (size_t)img * NPRED;
    for (int e = part * STPB + threadIdx.x; e < NPRED; e += SCB * STPB) {
        float s = sci[e];
        if (s != -INFINITY) {
            unsigned int sb = __float_as_uint(s);
            int bin = min((int)((sb - 0x3E800000u) >> 14), NBIN - 1);
            unsigned int pos = atomicAdd(&cursor[img * NBIN + bin], 1u);
            binned[(size_t)img * NPRED + pos] =
                ((unsigned long long)(~sb) << 32) | (unsigned int)e;
        }
    }
}

// ---------------------------------------------------------------------------
// NMS sort-and-sweep, round-8: binned candidate array -> contiguous tranche
// loads (no per-tranche rescans). Exactly equivalent to repeated
// argmax+suppress: candidates in (score desc, index asc) order; kept iff no
// earlier-kept box IoU>0.45. Validated structure from rounds 6-7: bulk-kill
// vs all kept (kills commute; sort restores order) -> compact -> bitonic
// sort -> windowed sweep (phase-1 parallel kill + wave-0 serial ballot
// sweep). Sticky degenerate case handled exactly. IoU decision exact:
// fdiv_rn(i,d) > 0.45f  <=>  (double)i > K*(double)d, K=(double)0.45f+2^-26
// (0.45f mantissa even => midpoint rounds down; 26b x 24b f64 product exact).
// ---------------------------------------------------------------------------
#define TPB      1024
#define TCAP     4096
#define FIRSTCAP 1024
#define SLOTS    4                  // TCAP / TPB
#define NW       (TPB / 64)         // 16 waves

__device__ __forceinline__ bool iou_gt(float Bx1, float By1, float Bx2, float By2,
                                       float BA,
                                       float cx1, float cy1, float cx2, float cy2,
                                       float ca, double K) {
    float lx = fmaxf(Bx1, cx1), ly = fmaxf(By1, cy1);
    float rx = fminf(Bx2, cx2), ry = fminf(By2, cy2);
    float ww = fmaxf(__fsub_rn(rx, lx), 0.0f);
    float hh = fmaxf(__fsub_rn(ry, ly), 0.0f);
    float inter = __fmul_rn(ww, hh);
    float denom = __fadd_rn(__fsub_rn(__fadd_rn(BA, ca), inter), 1e-9f);
    return ((double)inter > K * (double)denom);
}

__device__ __forceinline__ int blk_min(int v, int* s_red, int t, int wid) {
    #pragma unroll
    for (int off = 32; off; off >>= 1) v = min(v, __shfl_down(v, off));
    if ((t & 63) == 0) s_red[wid] = v;
    __syncthreads();
    int r = s_red[0];
    #pragma unroll
    for (int w = 1; w < NW; ++w) r = min(r, s_red[w]);
    return r;
}

__global__ __launch_bounds__(TPB)
void nms_kernel(const unsigned long long* __restrict__ binned,
                const unsigned int* __restrict__ IaG,
                const float4* __restrict__ box_g,
                int* __restrict__ selidx,
                int* __restrict__ selcnt) {
    __shared__ unsigned long long sbuf[TCAP];   // 32 KB sort buffer
    __shared__ unsigned int IaL[NBIN];          // 4 KB
    __shared__ float4 kbox[MAXDET];             // 4.8 KB
    __shared__ float  karea[MAXDET];            // 1.2 KB
    __shared__ unsigned char s_alive[TCAP];     // 4 KB
    __shared__ int s_red[NW];
    __shared__ int s_kept, s_sticky, s_stickyIdx, s_fillFrom, s_cnt2;

    const int img = blockIdx.x, t = threadIdx.x, wid = t >> 6;
    const float4* bxi = box_g + (size_t)img * NPRED;
    const unsigned long long* bin_img = binned + (size_t)img * NPRED;
    const double K = (double)0.45f + 0x1p-26;

    IaL[t] = IaG[img * NBIN + t];               // TPB == NBIN
    if (t == 0) { s_kept = 0; s_sticky = 0; }
    __syncthreads();
    const int n_valid = (int)IaL[0];

    int o = 0, b_hi = NBIN;
    bool firstT = true;
    for (;;) {
        if (s_kept >= MAXDET || s_sticky || o >= n_valid) break;   // uniform

        // ---- pick bin range [b_lo, b_hi): largest window <= cap ----
        const int cap = firstT ? FIRSTCAP : TCAP;
        __syncthreads();
        int vb = (t < b_hi && ((int)IaL[t] - o) <= cap) ? t : 0x7FFFFFFF;
        int b_lo = blk_min(vb, s_red, t, wid);
        if (b_lo == 0x7FFFFFFF && cap != TCAP) {     // fallback: full cap
            __syncthreads();
            vb = (t < b_hi && ((int)IaL[t] - o) <= TCAP) ? t : 0x7FFFFFFF;
            b_lo = blk_min(vb, s_red, t, wid);
        }
        int c;
        if (b_lo != 0x7FFFFFFF) {
            c = (int)IaL[b_lo] - o;
        } else {
            // pathological: single bin > TCAP; take highest nonempty, clamped
            __syncthreads();
            vb = (t < b_hi && ((int)IaL[t] - o) > 0) ? -t : 0x7FFFFFFF;
            int m2 = blk_min(vb, s_red, t, wid);
            b_lo = -m2;
            c = min((int)IaL[b_lo] - o, TCAP);
        }
        if (c <= 0) break;

        // ---- load tranche keys: contiguous coalesced slice of binned ----
        unsigned int um = 0;
        unsigned long long ukey[SLOTS];
        #pragma unroll
        for (int s = 0; s < SLOTS; ++s) {
            int p = s * TPB + t;
            bool av = (p < c);
            ukey[s] = av ? bin_img[o + p] : ~0ULL;
            if (av) um |= (1u << s);
        }
        const int kept0 = s_kept;          // uniform (barriers in pick above)

        // ---- bulk-kill vs ALL kept-so-far (kills commute; order restored
        //      by the sort) ----
        if (kept0 > 0 && um) {
            float ux1[SLOTS], uy1[SLOTS], ux2[SLOTS], uy2[SLOTS], uar[SLOTS];
            #pragma unroll
            for (int s = 0; s < SLOTS; ++s) {
                unsigned int ix = (um & (1u << s)) ? (unsigned int)ukey[s] : 0u;
                float4 b = bxi[ix];
                ux1[s] = b.x; uy1[s] = b.y; ux2[s] = b.z; uy2[s] = b.w;
                uar[s] = __fmul_rn(__fsub_rn(b.z, b.x), __fsub_rn(b.w, b.y));
            }
            for (int kb = 0; kb < kept0; ++kb) {
                float4 B = kbox[kb];
                float BA = karea[kb];
                #pragma unroll
                for (int s = 0; s < SLOTS; ++s) {
                    if (um & (1u << s)) {
                        if (iou_gt(B.x, B.y, B.z, B.w, BA,
                                   ux1[s], uy1[s], ux2[s], uy2[s], uar[s], K))
                            um &= ~(1u << s);
                    }
                }
                if (!um) break;
            }
        }
        // ---- compact survivors to the front of sbuf ----
        if (t == 0) s_cnt2 = 0;
        __syncthreads();
        int cnt2;
        if (kept0 == 0) {
            #pragma unroll
            for (int s = 0; s < SLOTS; ++s) {
                int p = s * TPB + t;
                if (p < c) sbuf[p] = ukey[s];
            }
            cnt2 = c;
            __syncthreads();
        } else {
            #pragma unroll
            for (int s = 0; s < SLOTS; ++s)
                if (um & (1u << s)) sbuf[atomicAdd(&s_cnt2, 1)] = ukey[s];
            __syncthreads();
            cnt2 = s_cnt2;
        }

        if (cnt2 > 0) {
            // ---- pad to power of two; bitonic sort ascending over
            //      (~scorebits, index) => score desc, index asc ----
            int m = 1; while (m < cnt2) m <<= 1;
            for (int p = t; p < m; p += TPB) if (p >= cnt2) sbuf[p] = ~0ULL;
            __syncthreads();
            for (int k = 2; k <= m; k <<= 1) {
                for (int j = k >> 1; j > 0; j >>= 1) {
                    for (int i = t; i < m; i += TPB) {
                        int l = i ^ j;
                        if (l > i) {
                            unsigned long long a = sbuf[i], b2 = sbuf[l];
                            if ((a > b2) == ((i & k) == 0)) { sbuf[i] = b2; sbuf[l] = a; }
                        }
                    }
                    __syncthreads();
                }
            }
            // ---- unpack: thread t owns sorted positions SLOTS*t.. ----
            unsigned int rm = 0;
            float rx1[SLOTS], ry1[SLOTS], rx2[SLOTS], ry2[SLOTS], rar[SLOTS];
            #pragma unroll
            for (int s = 0; s < SLOTS; ++s) {
                int p = t * SLOTS + s;
                bool av = (p < cnt2);
                unsigned int ix = av ? (unsigned int)sbuf[p] : 0u;
                float4 b = bxi[ix];
                rx1[s] = b.x; ry1[s] = b.y; rx2[s] = b.z; ry2[s] = b.w;
                rar[s] = __fmul_rn(__fsub_rn(b.z, b.x), __fsub_rn(b.w, b.y));
                if (av) rm |= (1u << s);
                s_alive[p] = av ? 1 : 0;
            }
            __syncthreads();

            const int nwin = (cnt2 + 63) >> 6;
            int applied = kept0;           // bulk-kill already covered [0,kept0)
            for (int g = 0; g < nwin; ++g) {
                int k0 = s_kept;           // uniform (post-barrier)
                // ---- phase-1: kill my candidates vs kept [applied,k0) ----
                if (rm) {
                    for (int kb = applied; kb < k0; ++kb) {
                        float4 B = kbox[kb];
                        float BA = karea[kb];
                        #pragma unroll
                        for (int s = 0; s < SLOTS; ++s) {
                            if (rm & (1u << s)) {
                                if (iou_gt(B.x, B.y, B.z, B.w, BA,
                                           rx1[s], ry1[s], rx2[s], ry2[s], rar[s], K)) {
                                    rm &= ~(1u << s);
                                    s_alive[t * SLOTS + s] = 0;
                                }
                            }
                        }
                        if (!rm) break;
                    }
                }
                applied = k0;
                __syncthreads();
                // ---- sweep window g: wave 0 only, no block barriers inside ----
                if (t < 64) {
                    int p = g * 64 + t;
                    int a = s_alive[p];
                    unsigned int ix = a ? (unsigned int)sbuf[p] : 0u;
                    float4 b = bxi[ix];
                    float cx1 = b.x, cy1 = b.y, cx2 = b.z, cy2 = b.w;
                    float car = __fmul_rn(__fsub_rn(b.z, b.x), __fsub_rn(b.w, b.y));
                    int kept = k0;
                    for (;;) {
                        unsigned long long bal = __ballot(a != 0);
                        if (!bal) break;
                        int f = (int)__builtin_ctzll(bal);
                        float Bx1 = __shfl(cx1, f), By1 = __shfl(cy1, f);
                        float Bx2 = __shfl(cx2, f), By2 = __shfl(cy2, f);
                        float BA  = __shfl(car, f);
                        int bidx  = __shfl((int)ix, f);
                        if (t == f) a = 0;
                        if (t == 0) {
                            selidx[img * MAXDET + kept] = bidx;
                            kbox[kept] = make_float4(Bx1, By1, Bx2, By2);
                            karea[kept] = BA;
                        }
                        // sticky check: reference-exact self-IoU
                        float dns = __fadd_rn(__fsub_rn(__fadd_rn(BA, BA), BA), 1e-9f);
                        if (!((double)BA > K * (double)dns)) {
                            if (t == 0) { s_sticky = 1; s_stickyIdx = bidx; s_fillFrom = kept + 1; }
                            kept = MAXDET;
                            break;
                        }
                        if (a) {
                            if (iou_gt(Bx1, By1, Bx2, By2, BA,
                                       cx1, cy1, cx2, cy2, car, K)) a = 0;
                        }
                        ++kept;
                        if (kept >= MAXDET) break;
                    }
                    if (t == 0) s_kept = kept;
                }
                __syncthreads();
                if (((t * SLOTS) >> 6) == g) rm = 0;       // my window swept
                if (s_kept >= MAXDET || s_sticky) break;   // uniform
            }
        }
        o = (int)IaL[b_lo];
        b_hi = b_lo;
        firstT = false;
    }
    // ---- finalize ----
    int keptF = s_kept;
    if (s_sticky) {
        for (int k2 = s_fillFrom + t; k2 < MAXDET; k2 += TPB)
            selidx[img * MAXDET + k2] = s_stickyIdx;
        keptF = MAXDET;
    }
    if (t == 0) selcnt[img] = keptF;
}

// ---------------------------------------------------------------------------
// Gather: writes every output element (zeros for padding rows — no memset
// needed). conf/cls/obj recomputed from pred with the identical rn ops.
// ---------------------------------------------------------------------------
#define GT 256

__global__ __launch_bounds__(GT)
void gather_kernel(const float* __restrict__ pred,
                   const float4* __restrict__ box,
                   const float* __restrict__ logits,
                   const int* __restrict__ selidx,
                   const int* __restrict__ selcnt,
                   float* __restrict__ out) {
    int tid = blockIdx.x * GT + threadIdx.x;
    if (tid >= BATCH * MAXDET * NDIM) return;
    int row = tid / NDIM, col = tid - row * NDIM;
    int img = row / MAXDET, det = row - img * MAXDET;
    float v = 0.0f;
    if (det < selcnt[img]) {
        int s = selidx[img * MAXDET + det];
        size_t g = (size_t)img * NPRED + s;
        if (col < 4) {
            float4 b = box[g];
            v = (col == 0) ? b.x : (col == 1) ? b.y : (col == 2) ? b.z : b.w;
        } else if (col == 6) {
            v = pred[g * 85 + 4];
        } else if (col >= 7) {
            v = logits[g * NC + (col - 7)];
        } else {
            const float* p = pred + g * 85;
            float obj = p[4];
            float best = -INFINITY; int bc = 0;
            #pragma unroll 8
            for (int c = 0; c < NC; ++c) {
                float q = __fmul_rn(p[5 + c], obj);
                if (q > best) { best = q; bc = c; }
            }
            v = (col == 4) ? best : (float)bc;
        }
    }
    out[tid] = v;
}

extern "C" void kernel_launch(void* const* d_in, const int* in_sizes, int n_in,
                              void* d_out, int out_size, void* d_ws, size_t ws_size,
                              hipStream_t stream) {
    const float* pred   = (const float*)d_in[0];
    const float* logits = (const float*)d_in[1];
    float* out = (float*)d_out;

    char* ws = (char*)d_ws;
    float*              sc     = (float*)(ws + WS_SC);
    float4*             box    = (float4*)(ws + WS_BOX);
    int*                selidx = (int*)(ws + WS_SELIDX);
    int*                selcnt = (int*)(ws + WS_SELCNT);
    unsigned int*       hist   = (unsigned int*)(ws + WS_HIST);
    unsigned int*       cursor = (unsigned int*)(ws + WS_CURSOR);
    unsigned int*       IaG    = (unsigned int*)(ws + WS_IA);
    unsigned long long* binned = (unsigned long long*)(ws + WS_BINNED);

    hipMemsetAsync(hist, 0, BATCH * NBIN * sizeof(unsigned int), stream);

    prep_kernel<<<BATCH * NPRED / PB, PREP_TPB, 0, stream>>>(pred, sc, box, hist);
    scan_kernel<<<BATCH, NBIN, 0, stream>>>(hist, IaG, cursor);
    scatter_kernel<<<BATCH * SCB, STPB, 0, stream>>>(sc, cursor, binned);
    nms_kernel<<<BATCH, TPB, 0, stream>>>(binned, IaG, box, selidx, selcnt);
    int gtot = BATCH * MAXDET * NDIM;
    gather_kernel<<<(gtot + GT - 1) / GT, GT, 0, stream>>>(pred, box, logits, selidx, selcnt, out);
}